// Round 1
// baseline (1043.233 us; speedup 1.0000x reference)
//
#include <hip/hip_runtime.h>
#include <math.h>

// Problem constants
#define N_ROWS 65536        // 16*4096
#define D 256
#define K 2048

// Output layout (floats) in d_out: z_q_st | loss | indices | perplexity
#define LOSS_OFF 16777216L
#define IDX_OFF  16777217L
#define PERP_OFF 16842753L

// Workspace layout (bytes)
#define WS_LOSS  8192       // float accumulator (hist uses [0,8192))
#define WS_ENORM 8448       // 2048 floats

// Argmin kernel tiling
#define BM 128
#define BN 128
#define DC 32
#define LSTR (BM + 4)       // 132: pad so transposed-store conflicts are only 4-way; b128 reads stay 16B-aligned & conflict-free

// ---------------------------------------------------------------- embed norms
__global__ __launch_bounds__(256) void enorm_kernel(const float* __restrict__ ew,
                                                    float* __restrict__ enorm) {
  const int lane = threadIdx.x & 63;
  const int wid  = threadIdx.x >> 6;
  const int row  = blockIdx.x * 4 + wid;      // 512 blocks * 4 waves = 2048 rows
  const float4 v = ((const float4*)(ew + (size_t)row * D))[lane];
  float s = v.x * v.x + v.y * v.y + v.z * v.z + v.w * v.w;
#pragma unroll
  for (int off = 32; off > 0; off >>= 1) s += __shfl_down(s, off, 64);
  if (lane == 0) enorm[row] = s;
}

// ------------------------------------------------------- fused GEMM + argmin
__global__ __launch_bounds__(256, 2) void argmin_kernel(
    const float* __restrict__ z, const float* __restrict__ ew,
    const float* __restrict__ enorm, float* __restrict__ out_idx,
    unsigned int* __restrict__ hist) {
  __shared__ float zt[DC][LSTR];   // transposed: zt[d][row]
  __shared__ float et[DC][LSTR];   // transposed: et[d][code]
  __shared__ float se[BN];
  __shared__ float red_d[BM][17];
  __shared__ int   red_i[BM][17];

  const int t  = threadIdx.x;
  const int tx = t & 15;          // code group
  const int ty = t >> 4;          // row group
  const int lr = t >> 3;          // 0..31 (loader row)
  const int ld = (t & 7) << 2;    // 0..28 (loader d offset)
  const size_t rowbase = (size_t)blockIdx.x * BM;

  float best[8];
  int   bidx[8];
#pragma unroll
  for (int i = 0; i < 8; ++i) { best[i] = 3.0e38f; bidx[i] = 0; }

  for (int kt = 0; kt < K / BN; ++kt) {
    __syncthreads();                          // protect se + prior dist reads
    if (t < BN) se[t] = enorm[kt * BN + t];

    float s[8][8];
#pragma unroll
    for (int i = 0; i < 8; ++i)
#pragma unroll
      for (int j = 0; j < 8; ++j) s[i][j] = 0.f;

    for (int dc = 0; dc < D / DC; ++dc) {
      __syncthreads();
#pragma unroll
      for (int s4 = 0; s4 < 4; ++s4) {
        const int r = lr + s4 * 32;
        const float4 va = *(const float4*)(z + (rowbase + r) * D + dc * DC + ld);
        zt[ld + 0][r] = va.x; zt[ld + 1][r] = va.y;
        zt[ld + 2][r] = va.z; zt[ld + 3][r] = va.w;
        const float4 vb = *(const float4*)(ew + (size_t)(kt * BN + r) * D + dc * DC + ld);
        et[ld + 0][r] = vb.x; et[ld + 1][r] = vb.y;
        et[ld + 2][r] = vb.z; et[ld + 3][r] = vb.w;
      }
      __syncthreads();
#pragma unroll 8
      for (int d = 0; d < DC; ++d) {
        const float4 a0 = *(const float4*)&zt[d][ty * 8];
        const float4 a1 = *(const float4*)&zt[d][ty * 8 + 4];
        const float4 b0 = *(const float4*)&et[d][tx * 8];
        const float4 b1 = *(const float4*)&et[d][tx * 8 + 4];
        const float a[8] = {a0.x, a0.y, a0.z, a0.w, a1.x, a1.y, a1.z, a1.w};
        const float b[8] = {b0.x, b0.y, b0.z, b0.w, b1.x, b1.y, b1.z, b1.w};
#pragma unroll
        for (int i = 0; i < 8; ++i)
#pragma unroll
          for (int j = 0; j < 8; ++j) s[i][j] = fmaf(a[i], b[j], s[i][j]);
      }
    }
    // distance = ||e||^2 - 2 z.e  (||z||^2 row-constant dropped; argmin invariant)
#pragma unroll
    for (int i = 0; i < 8; ++i) {
#pragma unroll
      for (int j = 0; j < 8; ++j) {
        const int c = tx * 8 + j;
        const float dist = se[c] - 2.0f * s[i][j];
        if (dist < best[i]) { best[i] = dist; bidx[i] = kt * BN + c; }
      }
    }
  }

  __syncthreads();
#pragma unroll
  for (int i = 0; i < 8; ++i) {
    red_d[ty * 8 + i][tx] = best[i];
    red_i[ty * 8 + i][tx] = bidx[i];
  }
  __syncthreads();
  if (t < BM) {
    float bd = red_d[t][0]; int bi = red_i[t][0];
#pragma unroll
    for (int j = 1; j < 16; ++j) {
      const float d2 = red_d[t][j]; const int i2 = red_i[t][j];
      if (d2 < bd || (d2 == bd && i2 < bi)) { bd = d2; bi = i2; }
    }
    out_idx[rowbase + t] = (float)bi;
    atomicAdd(&hist[bi], 1u);
  }
}

// ------------------------------------------------ gather + z_q_st + loss sum
__global__ __launch_bounds__(256) void gather_kernel(
    const float* __restrict__ z, const float* __restrict__ ew,
    const float* __restrict__ out_idx, float* __restrict__ out,
    float* __restrict__ loss_acc) {
  __shared__ float lred[4];
  const size_t NV = (size_t)N_ROWS * (D / 4);
  size_t v = (size_t)blockIdx.x * blockDim.x + threadIdx.x;
  const size_t stride = (size_t)gridDim.x * blockDim.x;
  float lsum = 0.f;
  for (; v < NV; v += stride) {
    const size_t row = v >> 6;
    const int d4 = (int)(v & 63);
    const int idx = (int)out_idx[row];
    const float4 e  = ((const float4*)(ew + (size_t)idx * D))[d4];
    const float4 zz = ((const float4*)z)[v];
    const float dx = e.x - zz.x, dy = e.y - zz.y, dz = e.z - zz.z, dw = e.w - zz.w;
    float4 q;
    q.x = zz.x + dx; q.y = zz.y + dy; q.z = zz.z + dz; q.w = zz.w + dw;
    ((float4*)out)[v] = q;
    lsum += dx * dx + dy * dy + dz * dz + dw * dw;
  }
#pragma unroll
  for (int off = 32; off > 0; off >>= 1) lsum += __shfl_down(lsum, off, 64);
  if ((threadIdx.x & 63) == 0) lred[threadIdx.x >> 6] = lsum;
  __syncthreads();
  if (threadIdx.x == 0) atomicAdd(loss_acc, lred[0] + lred[1] + lred[2] + lred[3]);
}

// ---------------------------------------------------- loss + perplexity
__global__ __launch_bounds__(256) void finalize_kernel(
    const unsigned int* __restrict__ hist, const float* __restrict__ loss_acc,
    float* __restrict__ out) {
  __shared__ float red[256];
  const int t = threadIdx.x;
  float local = 0.f;
  for (int k = t; k < K; k += 256) {
    const float p = (float)hist[k] * (1.0f / (float)N_ROWS);
    local += p * logf(p + 1e-10f);
  }
  red[t] = local;
  __syncthreads();
  for (int s = 128; s > 0; s >>= 1) {
    if (t < s) red[t] += red[t + s];
    __syncthreads();
  }
  if (t == 0) {
    out[LOSS_OFF] = 0.25f * loss_acc[0] * (1.0f / (float)(N_ROWS * (size_t)D));
    out[PERP_OFF] = expf(-red[0]);
  }
}

extern "C" void kernel_launch(void* const* d_in, const int* in_sizes, int n_in,
                              void* d_out, int out_size, void* d_ws, size_t ws_size,
                              hipStream_t stream) {
  const float* z  = (const float*)d_in[0];
  const float* ew = (const float*)d_in[1];
  float* out = (float*)d_out;
  unsigned int* hist = (unsigned int*)d_ws;
  float* loss_acc = (float*)((char*)d_ws + WS_LOSS);
  float* enorm    = (float*)((char*)d_ws + WS_ENORM);

  hipMemsetAsync(d_ws, 0, WS_LOSS + 4, stream);   // hist + loss accumulator
  enorm_kernel<<<K / 4, 256, 0, stream>>>(ew, enorm);
  argmin_kernel<<<N_ROWS / BM, 256, 0, stream>>>(z, ew, enorm, out + IDX_OFF, hist);
  gather_kernel<<<2048, 256, 0, stream>>>(z, ew, out + IDX_OFF, out, loss_acc);
  finalize_kernel<<<1, 256, 0, stream>>>(hist, loss_acc, out);
}

// Round 2
// 534.189 us; speedup vs baseline: 1.9529x; 1.9529x over previous
//
#include <hip/hip_runtime.h>
#include <math.h>

#define N_ROWS 65536
#define D 256
#define K 2048

// d_out float layout: z_q_st | loss | indices | perplexity
#define LOSS_OFF 16777216L
#define IDX_OFF  16777217L
#define PERP_OFF 16842753L

// ws byte layout
#define WS_HIST    0        // 2048 * 4
#define WS_LOSS    8192
#define WS_FLAGCNT 8196
#define WS_ENORM   8448     // 2048 * 4
#define WS_FLAGS   16640    // 65536 * 4
#define WS_BPK     524288   // 8 planes * 2048 * 64B = 1 MB

#define MARGIN 0.15f

typedef _Float16 half8 __attribute__((ext_vector_type(8)));
typedef float floatx4 __attribute__((ext_vector_type(4)));

__device__ __forceinline__ void gload16(const void* g, void* l) {
  __builtin_amdgcn_global_load_lds((const __attribute__((address_space(1))) void*)g,
                                   (__attribute__((address_space(3))) void*)l, 16, 0, 0);
}

// ---------------- convert A: z fp32 -> 16 k-planes of fp16 (hi planes 0-7, lo 8-15)
// Apk[plane][row][32 halfs], plane p covers k in [p*32, p*32+32)
__global__ __launch_bounds__(256) void convertA_kernel(const float* __restrict__ z,
                                                       uint4* __restrict__ apk) {
  const int gid = blockIdx.x * 256 + threadIdx.x;   // 524288
  const int row = gid >> 3, c = gid & 7;
  const float4* s4 = (const float4*)(z + (size_t)row * D + c * 32);
  float buf[32];
#pragma unroll
  for (int q = 0; q < 8; ++q) *(float4*)&buf[q * 4] = s4[q];
  _Float16 hi[32], lo[32];
#pragma unroll
  for (int k = 0; k < 32; ++k) {
    const float v = buf[k];
    const _Float16 h = (_Float16)v;
    hi[k] = h;
    lo[k] = (_Float16)(v - (float)h);
  }
  uint4* dhi = apk + ((size_t)c * N_ROWS + row) * 4;
  uint4* dlo = apk + ((size_t)(c + 8) * N_ROWS + row) * 4;
#pragma unroll
  for (int i = 0; i < 4; ++i) dhi[i] = ((const uint4*)hi)[i];
#pragma unroll
  for (int i = 0; i < 4; ++i) dlo[i] = ((const uint4*)lo)[i];
}

// ---------------- convert B: ew fp32 -> 8 k-planes fp16 (e_hi); Bpk[plane][code][32]
__global__ __launch_bounds__(256) void convertB_kernel(const float* __restrict__ ew,
                                                       uint4* __restrict__ bpk) {
  const int gid = blockIdx.x * 256 + threadIdx.x;   // 16384
  const int code = gid >> 3, c = gid & 7;
  const float4* s4 = (const float4*)(ew + (size_t)code * D + c * 32);
  float buf[32];
#pragma unroll
  for (int q = 0; q < 8; ++q) *(float4*)&buf[q * 4] = s4[q];
  _Float16 hi[32];
#pragma unroll
  for (int k = 0; k < 32; ++k) hi[k] = (_Float16)buf[k];
  uint4* dhi = bpk + ((size_t)c * K + code) * 4;
#pragma unroll
  for (int i = 0; i < 4; ++i) dhi[i] = ((const uint4*)hi)[i];
}

// ---------------- exact fp32 ||e||^2
__global__ __launch_bounds__(256) void enorm_kernel(const float* __restrict__ ew,
                                                    float* __restrict__ enorm) {
  const int lane = threadIdx.x & 63;
  const int wid  = threadIdx.x >> 6;
  const int row  = blockIdx.x * 4 + wid;
  const float4 v = ((const float4*)(ew + (size_t)row * D))[lane];
  float s = v.x * v.x + v.y * v.y + v.z * v.z + v.w * v.w;
#pragma unroll
  for (int off = 32; off > 0; off >>= 1) s += __shfl_down(s, off, 64);
  if (lane == 0) enorm[row] = s;
}

// ---------------- MFMA distance GEMM + fused argmin (approx, with margin flags)
__global__ void argmin_mfma_kernel(const char* __restrict__ apk,
                                   const char* __restrict__ bpk,
                                   const float* __restrict__ enorm,
                                   float* __restrict__ out_idx,
                                   int* __restrict__ flagcnt,
                                   int* __restrict__ flags) {
  __shared__ __align__(16) char As[16384];  // [sub][128 rows][32 halfs]
  __shared__ __align__(16) char Bs[16384];  // [sub][128 codes][32 halfs]

  const int t = threadIdx.x;
  const int lane = t & 63, w = t >> 6;
  const int quad = lane >> 4, l15 = lane & 15;
  const int wrow = w * 32;                      // wave owns rows wrow..wrow+31
  const size_t rowbase = (size_t)blockIdx.x * 128;

  float best[8], sec[8];
  int bidx[8];
#pragma unroll
  for (int s = 0; s < 8; ++s) { best[s] = 3.0e38f; sec[s] = 3.0e38f; bidx[s] = 0; }

#pragma unroll 1
  for (int nt = 0; nt < 16; ++nt) {
    floatx4 acc[2][8];
#pragma unroll
    for (int i = 0; i < 2; ++i)
#pragma unroll
      for (int j = 0; j < 8; ++j) acc[i][j] = 0;

    const size_t ntb = (size_t)nt * 128 * 64;   // B tile byte offset within plane

#pragma unroll 1
    for (int ks = 0; ks < 8; ++ks) {
      __syncthreads();
      // stage: 32 segs of 1KB (16 A + 16 B); wave w does segs w*8..w*8+7
#pragma unroll
      for (int c = 0; c < 8; ++c) {
        const int seg = w * 8 + c;
        if (seg < 16) {
          const int sub = seg >> 3, cb = seg & 7;
          const int plane = 2 * ks + sub;             // 0..15
          const char* g = apk + ((size_t)plane << 22) + (rowbase << 6)
                        + (size_t)(cb * 1024 + lane * 16);
          gload16(g, As + seg * 1024);
        } else {
          const int s2 = seg - 16;
          const int sub = s2 >> 3, cb = s2 & 7;
          const int plane = (2 * ks + sub) & 7;       // e_hi reused for lo slot
          const char* g = bpk + ((size_t)plane << 17) + ntb
                        + (size_t)(cb * 1024 + lane * 16);
          gload16(g, Bs + s2 * 1024);
        }
      }
      __syncthreads();

#pragma unroll
      for (int sub = 0; sub < 2; ++sub) {
        half8 av[2], bv[8];
#pragma unroll
        for (int i = 0; i < 2; ++i)
          av[i] = *(const half8*)(As + sub * 8192 + (wrow + i * 16 + l15) * 64 + quad * 16);
#pragma unroll
        for (int j = 0; j < 8; ++j)
          bv[j] = *(const half8*)(Bs + sub * 8192 + (j * 16 + l15) * 64 + quad * 16);
#pragma unroll
        for (int i = 0; i < 2; ++i)
#pragma unroll
          for (int j = 0; j < 8; ++j)
            acc[i][j] = __builtin_amdgcn_mfma_f32_16x16x32_f16(av[i], bv[j], acc[i][j], 0, 0, 0);
      }
    }

    // epilogue: dist = ||e||^2 - 2*dot ; per-slot best/second tracking
#pragma unroll
    for (int j = 0; j < 8; ++j) {
      const int cg = nt * 128 + j * 16 + l15;
      const float en = enorm[cg];
#pragma unroll
      for (int i = 0; i < 2; ++i)
#pragma unroll
        for (int r = 0; r < 4; ++r) {
          const float dv = fmaf(-2.0f, acc[i][j][r], en);
          const int s = i * 4 + r;
          if (dv < best[s]) { sec[s] = best[s]; best[s] = dv; bidx[s] = cg; }
          else if (dv < sec[s]) sec[s] = dv;
        }
    }
  }

  // merge across the 16 lanes (same quad group) holding each row
#pragma unroll
  for (int s = 0; s < 8; ++s) {
    float b = best[s], s2 = sec[s];
    int bi = bidx[s];
#pragma unroll
    for (int m = 1; m < 16; m <<= 1) {
      const float ob = __shfl_xor(b, m, 64);
      const float os = __shfl_xor(s2, m, 64);
      const int   oi = __shfl_xor(bi, m, 64);
      const bool take = (ob < b) || (ob == b && oi < bi);
      const float loser = take ? b : ob;
      if (take) { b = ob; bi = oi; }
      s2 = fminf(fminf(s2, os), loser);
    }
    if (l15 == 0) {
      const int rowg = (int)rowbase + wrow + (s >> 2) * 16 + quad * 4 + (s & 3);
      out_idx[rowg] = (float)bi;
      if (s2 - b < MARGIN) {
        const int p = atomicAdd(flagcnt, 1);
        flags[p] = rowg;
      }
    }
  }
}

// ---------------- exact fp32 rescue for near-tie rows
__global__ __launch_bounds__(256) void rescue_kernel(const float* __restrict__ z,
                                                     const float* __restrict__ ew,
                                                     const float* __restrict__ enorm,
                                                     const int* __restrict__ flagcnt,
                                                     const int* __restrict__ flags,
                                                     float* __restrict__ out_idx) {
  __shared__ __align__(16) float zs[8][256];
  __shared__ unsigned long long bkey[8];
  const int t = threadIdx.x;
  const int cnt = flagcnt[0];
  for (int grp = blockIdx.x; grp * 8 < cnt; grp += gridDim.x) {
    const int nr = min(8, cnt - grp * 8);
    __syncthreads();
    {
      const int rr = t >> 5, d8 = t & 31;
      if (rr < nr) {
        const int row = flags[grp * 8 + rr];
        const float4* s = (const float4*)(z + (size_t)row * D + d8 * 8);
        *(float4*)&zs[rr][d8 * 8]     = s[0];
        *(float4*)&zs[rr][d8 * 8 + 4] = s[1];
      }
    }
    if (t < 8) bkey[t] = ~0ULL;
    __syncthreads();

    unsigned long long mykey[8];
#pragma unroll
    for (int rr = 0; rr < 8; ++rr) mykey[rr] = ~0ULL;

    for (int cc = 0; cc < 8; ++cc) {
      const int c = cc * 256 + t;
      float acc[8];
#pragma unroll
      for (int rr = 0; rr < 8; ++rr) acc[rr] = 0.f;
      const float4* ev = (const float4*)(ew + (size_t)c * D);
      for (int d4 = 0; d4 < 64; ++d4) {
        const float4 e = ev[d4];
#pragma unroll
        for (int rr = 0; rr < 8; ++rr) {
          const float4 zz = *(const float4*)&zs[rr][d4 * 4];
          float a = acc[rr];
          a = fmaf(e.x, zz.x, a); a = fmaf(e.y, zz.y, a);
          a = fmaf(e.z, zz.z, a); a = fmaf(e.w, zz.w, a);
          acc[rr] = a;
        }
      }
      const float en = enorm[c];
#pragma unroll
      for (int rr = 0; rr < 8; ++rr) {
        const float dv = fmaf(-2.0f, acc[rr], en);
        const unsigned b = __float_as_uint(dv);
        const unsigned k32 = b ^ ((unsigned)((int)b >> 31) | 0x80000000u);  // sortable
        const unsigned long long key = ((unsigned long long)k32 << 32) | (unsigned)c;
        if (key < mykey[rr]) mykey[rr] = key;
      }
    }
#pragma unroll
    for (int rr = 0; rr < 8; ++rr)
      if (rr < nr) atomicMin(&bkey[rr], mykey[rr]);
    __syncthreads();
    if (t < nr) out_idx[flags[grp * 8 + t]] = (float)(unsigned)(bkey[t] & 0xFFFFFFFFu);
  }
}

// ---------------- gather + z_q_st + loss sum + histogram
__global__ __launch_bounds__(256) void gather_kernel(const float* __restrict__ z,
                                                     const float* __restrict__ ew,
                                                     const float* __restrict__ out_idx,
                                                     float* __restrict__ out,
                                                     float* __restrict__ loss_acc,
                                                     int* __restrict__ hist) {
  __shared__ float lred[4];
  const size_t NV = (size_t)N_ROWS * (D / 4);
  size_t v = (size_t)blockIdx.x * blockDim.x + threadIdx.x;
  const size_t stride = (size_t)gridDim.x * blockDim.x;
  float lsum = 0.f;
  for (; v < NV; v += stride) {
    const size_t row = v >> 6;
    const int d4 = (int)(v & 63);
    const int idx = (int)out_idx[row];
    if (d4 == 0) atomicAdd(&hist[idx], 1);
    const float4 e  = ((const float4*)(ew + (size_t)idx * D))[d4];
    const float4 zz = ((const float4*)z)[v];
    const float dx = e.x - zz.x, dy = e.y - zz.y, dz = e.z - zz.z, dw = e.w - zz.w;
    float4 q;
    q.x = zz.x + dx; q.y = zz.y + dy; q.z = zz.z + dz; q.w = zz.w + dw;
    ((float4*)out)[v] = q;
    lsum += dx * dx + dy * dy + dz * dz + dw * dw;
  }
#pragma unroll
  for (int off = 32; off > 0; off >>= 1) lsum += __shfl_down(lsum, off, 64);
  if ((threadIdx.x & 63) == 0) lred[threadIdx.x >> 6] = lsum;
  __syncthreads();
  if (threadIdx.x == 0) atomicAdd(loss_acc, lred[0] + lred[1] + lred[2] + lred[3]);
}

// ---------------- loss + perplexity
__global__ __launch_bounds__(256) void finalize_kernel(const int* __restrict__ hist,
                                                       const float* __restrict__ loss_acc,
                                                       float* __restrict__ out) {
  __shared__ float red[256];
  const int t = threadIdx.x;
  float local = 0.f;
  for (int k = t; k < K; k += 256) {
    const float p = (float)hist[k] * (1.0f / (float)N_ROWS);
    local += p * logf(p + 1e-10f);
  }
  red[t] = local;
  __syncthreads();
  for (int s = 128; s > 0; s >>= 1) {
    if (t < s) red[t] += red[t + s];
    __syncthreads();
  }
  if (t == 0) {
    out[LOSS_OFF] = 0.25f * loss_acc[0] * (1.0f / (float)((size_t)N_ROWS * D));
    out[PERP_OFF] = expf(-red[0]);
  }
}

extern "C" void kernel_launch(void* const* d_in, const int* in_sizes, int n_in,
                              void* d_out, int out_size, void* d_ws, size_t ws_size,
                              hipStream_t stream) {
  const float* z  = (const float*)d_in[0];
  const float* ew = (const float*)d_in[1];
  float* out = (float*)d_out;

  char* ws = (char*)d_ws;
  int*   hist     = (int*)(ws + WS_HIST);
  float* loss_acc = (float*)(ws + WS_LOSS);
  int*   flagcnt  = (int*)(ws + WS_FLAGCNT);
  float* enorm    = (float*)(ws + WS_ENORM);
  int*   flags    = (int*)(ws + WS_FLAGS);
  char*  bpk      = ws + WS_BPK;
  char*  apk      = (char*)d_out;          // 64 MB scratch inside z_q region

  hipMemsetAsync(d_ws, 0, 8448, stream);   // hist + loss + flagcnt

  convertA_kernel<<<2048, 256, 0, stream>>>(z, (uint4*)apk);
  convertB_kernel<<<64, 256, 0, stream>>>(ew, (uint4*)bpk);
  enorm_kernel<<<K / 4, 256, 0, stream>>>(ew, enorm);
  argmin_mfma_kernel<<<N_ROWS / 128, 256, 0, stream>>>(apk, bpk, enorm,
                                                       out + IDX_OFF, flagcnt, flags);
  rescue_kernel<<<256, 256, 0, stream>>>(z, ew, enorm, flagcnt, flags, out + IDX_OFF);
  gather_kernel<<<2048, 256, 0, stream>>>(z, ew, out + IDX_OFF, out, loss_acc, hist);
  finalize_kernel<<<1, 256, 0, stream>>>(hist, loss_acc, out);
}

// Round 3
// 441.898 us; speedup vs baseline: 2.3608x; 1.2089x over previous
//
#include <hip/hip_runtime.h>
#include <math.h>

#define N_ROWS 65536
#define D 256
#define K 2048

// d_out float layout: z_q_st | loss | indices | perplexity
#define LOSS_OFF 16777216L
#define IDX_OFF  16777217L
#define PERP_OFF 16842753L

// ws byte layout
#define WS_HIST    0           // 2048*4
#define WS_LOSS    8192
#define WS_FLAGCNT 8196
#define WS_ENORM   8448        // 2048*4
#define WS_ZNORM   16640       // 65536*4
#define WS_FLAGS   278784      // 65536*4
#define WS_BPK     540928      // 1 MB  [nt][kc][code][quad] fp16

#define MARGIN 0.25f

typedef _Float16 half8 __attribute__((ext_vector_type(8)));
typedef float floatx4 __attribute__((ext_vector_type(4)));

__device__ __forceinline__ void gload16(const void* g, void* l) {
  __builtin_amdgcn_global_load_lds((const __attribute__((address_space(1))) void*)g,
                                   (__attribute__((address_space(3))) void*)l, 16, 0, 0);
}

// ---- convert A: z fp32 -> fp16 frag-packed apk[kc][row][quad] + znorm
__global__ __launch_bounds__(256) void convertA_kernel(const float* __restrict__ z,
                                                       uint4* __restrict__ apk,
                                                       float* __restrict__ znorm) {
  const int gid = blockIdx.x * 256 + threadIdx.x;   // 524288
  const int row = gid >> 3, c = gid & 7;
  const float4* s4 = (const float4*)(z + (size_t)row * D + c * 32);
  float buf[32];
#pragma unroll
  for (int q = 0; q < 8; ++q) *(float4*)&buf[q * 4] = s4[q];
  float s = 0.f;
#pragma unroll
  for (int k = 0; k < 32; ++k) s = fmaf(buf[k], buf[k], s);
  s += __shfl_xor(s, 1, 64); s += __shfl_xor(s, 2, 64); s += __shfl_xor(s, 4, 64);
  if ((threadIdx.x & 7) == 0) znorm[row] = s;
  _Float16 hi[32];
#pragma unroll
  for (int k = 0; k < 32; ++k) hi[k] = (_Float16)buf[k];
  uint4* d = apk + ((size_t)c * N_ROWS + row) * 4;
#pragma unroll
  for (int i = 0; i < 4; ++i) d[i] = ((const uint4*)hi)[i];
}

// ---- convert B: ew fp32 -> fp16 bpk[nt][kc][code][quad] + enorm (exact fp32)
__global__ __launch_bounds__(256) void convertB_kernel(const float* __restrict__ ew,
                                                       uint4* __restrict__ bpk,
                                                       float* __restrict__ enorm) {
  const int gid = blockIdx.x * 256 + threadIdx.x;   // 16384
  const int code = gid >> 3, c = gid & 7;
  const float4* s4 = (const float4*)(ew + (size_t)code * D + c * 32);
  float buf[32];
#pragma unroll
  for (int q = 0; q < 8; ++q) *(float4*)&buf[q * 4] = s4[q];
  float s = 0.f;
#pragma unroll
  for (int k = 0; k < 32; ++k) s = fmaf(buf[k], buf[k], s);
  s += __shfl_xor(s, 1, 64); s += __shfl_xor(s, 2, 64); s += __shfl_xor(s, 4, 64);
  if ((threadIdx.x & 7) == 0) enorm[code] = s;
  _Float16 hi[32];
#pragma unroll
  for (int k = 0; k < 32; ++k) hi[k] = (_Float16)buf[k];
  const int nt = code >> 7, cl = code & 127;
  uint4* d = bpk + (size_t)nt * 4096 + c * 512 + cl * 4;
#pragma unroll
  for (int i = 0; i < 4; ++i) d[i] = ((const uint4*)hi)[i];
}

// ---- MFMA distance GEMM, A in registers (read once), fused argmin + loss
__global__ __launch_bounds__(256, 2) void argmin_mfma_kernel(
    const char* __restrict__ apk, const char* __restrict__ bpk,
    const float* __restrict__ enorm, const float* __restrict__ znorm,
    float* __restrict__ out_idx, float* __restrict__ loss_acc,
    int* __restrict__ flagcnt, int* __restrict__ flags) {
  __shared__ __align__(16) char Bs[65536];   // [kc][128 codes][quad] one nt tile

  const int t = threadIdx.x, lane = t & 63, w = t >> 6;
  const int quad = lane >> 4, l15 = lane & 15;
  const int wrow = w * 32;                   // wave owns rows wrow..wrow+31
  const size_t rowbase = (size_t)blockIdx.x * 128;

  // A fragments: 8 k-chunks x 2 row-tiles, loaded once (64 VGPRs)
  half8 a[8][2];
  {
    const char* ab = apk + ((rowbase + wrow + l15) * 4 + (size_t)quad) * 16;
#pragma unroll
    for (int kc = 0; kc < 8; ++kc)
#pragma unroll
      for (int rt = 0; rt < 2; ++rt)
        a[kc][rt] = *(const half8*)(ab + (size_t)kc * 4194304 + rt * 1024);
  }

  float best[8], sec[8]; int bidx[8];
#pragma unroll
  for (int s = 0; s < 8; ++s) { best[s] = 3.0e38f; sec[s] = 3.0e38f; bidx[s] = 0; }

#pragma unroll 1
  for (int nt = 0; nt < 16; ++nt) {
    __syncthreads();
#pragma unroll
    for (int i = 0; i < 16; ++i)
      gload16(bpk + (size_t)nt * 65536 + i * 4096 + t * 16, Bs + i * 4096 + t * 16);
    __syncthreads();

    floatx4 acc[2][8];
#pragma unroll
    for (int rt = 0; rt < 2; ++rt)
#pragma unroll
      for (int ct = 0; ct < 8; ++ct) acc[rt][ct] = 0;

#pragma unroll
    for (int kc = 0; kc < 8; ++kc) {
      half8 bv[8];
#pragma unroll
      for (int ct = 0; ct < 8; ++ct)
        bv[ct] = *(const half8*)(Bs + kc * 8192 + (ct * 16 + l15) * 64 + quad * 16);
#pragma unroll
      for (int ct = 0; ct < 8; ++ct) {
        acc[0][ct] = __builtin_amdgcn_mfma_f32_16x16x32_f16(a[kc][0], bv[ct], acc[0][ct], 0, 0, 0);
        acc[1][ct] = __builtin_amdgcn_mfma_f32_16x16x32_f16(a[kc][1], bv[ct], acc[1][ct], 0, 0, 0);
      }
    }

    // dist = ||e||^2 - 2 z.e  (row const ||z||^2 added only into loss)
#pragma unroll
    for (int ct = 0; ct < 8; ++ct) {
      const int cg = nt * 128 + ct * 16 + l15;
      const float en = enorm[cg];
#pragma unroll
      for (int rt = 0; rt < 2; ++rt)
#pragma unroll
        for (int r = 0; r < 4; ++r) {
          const float dv = fmaf(-2.0f, acc[rt][ct][r], en);
          const int s = rt * 4 + r;
          if (dv < best[s]) { sec[s] = best[s]; best[s] = dv; bidx[s] = cg; }
          else if (dv < sec[s]) sec[s] = dv;
        }
    }
  }

  // merge across the 16 lanes holding each row + loss + margin flags
  float lsum = 0.f;
#pragma unroll
  for (int s = 0; s < 8; ++s) {
    float b = best[s], s2 = sec[s];
    int bi = bidx[s];
#pragma unroll
    for (int m = 1; m < 16; m <<= 1) {
      const float ob = __shfl_xor(b, m, 64);
      const float os = __shfl_xor(s2, m, 64);
      const int   oi = __shfl_xor(bi, m, 64);
      const bool take = (ob < b) || (ob == b && oi < bi);
      const float loser = take ? b : ob;
      if (take) { b = ob; bi = oi; }
      s2 = fminf(fminf(s2, os), loser);
    }
    if (l15 == 0) {
      const int rowg = (int)rowbase + wrow + (s >> 2) * 16 + quad * 4 + (s & 3);
      out_idx[rowg] = (float)bi;
      lsum += b + znorm[rowg];
      if (s2 - b < MARGIN) {
        const int p = atomicAdd(flagcnt, 1);
        flags[p] = rowg;
      }
    }
  }
  lsum += __shfl_down(lsum, 16, 64);
  lsum += __shfl_down(lsum, 32, 64);
  if (lane == 0) atomicAdd(loss_acc, lsum);
}

// ---- exact fp32 rescue for near-tie rows (indices only)
__global__ __launch_bounds__(256) void rescue_kernel(const float* __restrict__ z,
                                                     const float* __restrict__ ew,
                                                     const float* __restrict__ enorm,
                                                     const int* __restrict__ flagcnt,
                                                     const int* __restrict__ flags,
                                                     float* __restrict__ out_idx) {
  __shared__ __align__(16) float zs[8][256];
  __shared__ unsigned long long bkey[8];
  const int t = threadIdx.x;
  const int cnt = flagcnt[0];
  for (int grp = blockIdx.x; grp * 8 < cnt; grp += gridDim.x) {
    const int nr = min(8, cnt - grp * 8);
    __syncthreads();
    {
      const int rr = t >> 5, d8 = t & 31;
      if (rr < nr) {
        const int row = flags[grp * 8 + rr];
        const float4* s = (const float4*)(z + (size_t)row * D + d8 * 8);
        *(float4*)&zs[rr][d8 * 8]     = s[0];
        *(float4*)&zs[rr][d8 * 8 + 4] = s[1];
      }
    }
    if (t < 8) bkey[t] = ~0ULL;
    __syncthreads();

    unsigned long long mykey[8];
#pragma unroll
    for (int rr = 0; rr < 8; ++rr) mykey[rr] = ~0ULL;

    for (int cc = 0; cc < 8; ++cc) {
      const int c = cc * 256 + t;
      float acc[8];
#pragma unroll
      for (int rr = 0; rr < 8; ++rr) acc[rr] = 0.f;
      const float4* ev = (const float4*)(ew + (size_t)c * D);
      for (int d4 = 0; d4 < 64; ++d4) {
        const float4 e = ev[d4];
#pragma unroll
        for (int rr = 0; rr < 8; ++rr) {
          const float4 zz = *(const float4*)&zs[rr][d4 * 4];
          float a = acc[rr];
          a = fmaf(e.x, zz.x, a); a = fmaf(e.y, zz.y, a);
          a = fmaf(e.z, zz.z, a); a = fmaf(e.w, zz.w, a);
          acc[rr] = a;
        }
      }
      const float en = enorm[c];
#pragma unroll
      for (int rr = 0; rr < 8; ++rr) {
        const float dv = fmaf(-2.0f, acc[rr], en);
        const unsigned b = __float_as_uint(dv);
        const unsigned k32 = b ^ ((unsigned)((int)b >> 31) | 0x80000000u);
        const unsigned long long key = ((unsigned long long)k32 << 32) | (unsigned)c;
        if (key < mykey[rr]) mykey[rr] = key;
      }
    }
#pragma unroll
    for (int rr = 0; rr < 8; ++rr)
      if (rr < nr) atomicMin(&bkey[rr], mykey[rr]);
    __syncthreads();
    if (t < nr) out_idx[flags[grp * 8 + t]] = (float)(unsigned)(bkey[t] & 0xFFFFFFFFu);
  }
}

// ---- gather: z_q_st value == ew[idx]; also histogram (post-rescue)
__global__ __launch_bounds__(256) void gather_kernel(const float* __restrict__ ew,
                                                     const float* __restrict__ out_idx,
                                                     float* __restrict__ out,
                                                     int* __restrict__ hist) {
  const size_t NV = (size_t)N_ROWS * (D / 4);
  size_t v = (size_t)blockIdx.x * 256 + threadIdx.x;
  const size_t stride = (size_t)gridDim.x * 256;
  for (; v < NV; v += stride) {
    const size_t row = v >> 6;
    const int d4 = (int)(v & 63);
    const int idx = (int)out_idx[row];
    if (d4 == 0) atomicAdd(&hist[idx], 1);
    ((float4*)out)[v] = ((const float4*)ew)[(size_t)idx * 64 + d4];
  }
}

// ---- loss + perplexity
__global__ __launch_bounds__(256) void finalize_kernel(const int* __restrict__ hist,
                                                       const float* __restrict__ loss_acc,
                                                       float* __restrict__ out) {
  __shared__ float red[256];
  const int t = threadIdx.x;
  float local = 0.f;
  for (int k = t; k < K; k += 256) {
    const float p = (float)hist[k] * (1.0f / (float)N_ROWS);
    local += p * logf(p + 1e-10f);
  }
  red[t] = local;
  __syncthreads();
  for (int s = 128; s > 0; s >>= 1) {
    if (t < s) red[t] += red[t + s];
    __syncthreads();
  }
  if (t == 0) {
    out[LOSS_OFF] = 0.25f * loss_acc[0] * (1.0f / (float)((size_t)N_ROWS * D));
    out[PERP_OFF] = expf(-red[0]);
  }
}

extern "C" void kernel_launch(void* const* d_in, const int* in_sizes, int n_in,
                              void* d_out, int out_size, void* d_ws, size_t ws_size,
                              hipStream_t stream) {
  const float* z  = (const float*)d_in[0];
  const float* ew = (const float*)d_in[1];
  float* out = (float*)d_out;

  char* ws = (char*)d_ws;
  int*   hist     = (int*)(ws + WS_HIST);
  float* loss_acc = (float*)(ws + WS_LOSS);
  int*   flagcnt  = (int*)(ws + WS_FLAGCNT);
  float* enorm    = (float*)(ws + WS_ENORM);
  float* znorm    = (float*)(ws + WS_ZNORM);
  int*   flags    = (int*)(ws + WS_FLAGS);
  char*  bpk      = ws + WS_BPK;
  char*  apk      = (char*)d_out;          // 32 MB scratch in z_q region (overwritten by gather)

  hipMemsetAsync(d_ws, 0, 8448, stream);   // hist + loss + flagcnt

  convertA_kernel<<<2048, 256, 0, stream>>>(z, (uint4*)apk, znorm);
  convertB_kernel<<<64, 256, 0, stream>>>(ew, (uint4*)bpk, enorm);
  argmin_mfma_kernel<<<N_ROWS / 128, 256, 0, stream>>>(apk, bpk, enorm, znorm,
                                                       out + IDX_OFF, loss_acc,
                                                       flagcnt, flags);
  rescue_kernel<<<256, 256, 0, stream>>>(z, ew, enorm, flagcnt, flags, out + IDX_OFF);
  gather_kernel<<<2048, 256, 0, stream>>>(ew, out + IDX_OFF, out, hist);
  finalize_kernel<<<1, 256, 0, stream>>>(hist, loss_acc, out);
}